// Round 1
// baseline (3409.583 us; speedup 1.0000x reference)
//
#include <hip/hip_runtime.h>

// ---------------- degree / dinv ----------------
__global__ __launch_bounds__(256) void init_deg(float* deg, int n) {
    int i = blockIdx.x * 256 + threadIdx.x;
    if (i < n) deg[i] = 1.0f;   // self-loop contributes 1
}

__global__ __launch_bounds__(256) void deg_edges(const int* __restrict__ row, float* deg, int E) {
    int e = blockIdx.x * 256 + threadIdx.x;
    if (e < E) atomicAdd(&deg[row[e]], 1.0f);
}

__global__ __launch_bounds__(256) void make_dinv(float* deg, int n) {
    int i = blockIdx.x * 256 + threadIdx.x;
    if (i < n) deg[i] = rsqrtf(deg[i]);   // deg >= 1 always
}

// ---------------- fp32 tiled GEMM: C[M,N] = A[M,K] @ B[K,N] ----------------
// TM=TN=64, TK=32, 256 threads, 4x4 acc per thread. N,K multiples of 32/64.
__global__ __launch_bounds__(256) void gemm64(const float* __restrict__ A,
                                              const float* __restrict__ B,
                                              float* __restrict__ C,
                                              int M, int N, int K) {
    __shared__ float As[32][65];   // [k][m], +1 pad
    __shared__ float Bs[32][65];   // [k][n], +1 pad
    const int bm = blockIdx.x * 64;
    const int bn = blockIdx.y * 64;
    const int tid = threadIdx.x;
    const int tx = tid & 15;       // n-group
    const int ty = tid >> 4;       // m-group
    float acc[4][4] = {};

    for (int k0 = 0; k0 < K; k0 += 32) {
        #pragma unroll
        for (int i = 0; i < 8; ++i) {        // A tile: 64x32
            int t = tid + i * 256;
            int r = t >> 5, c = t & 31;
            int gr = bm + r;
            float v = 0.f;
            if (gr < M) v = A[(size_t)gr * K + k0 + c];
            As[c][r] = v;
        }
        #pragma unroll
        for (int i = 0; i < 8; ++i) {        // B tile: 32x64
            int t = tid + i * 256;
            int r = t >> 6, c = t & 63;
            Bs[r][c] = B[(size_t)(k0 + r) * N + bn + c];
        }
        __syncthreads();
        #pragma unroll
        for (int k = 0; k < 32; ++k) {
            float av[4], bv[4];
            #pragma unroll
            for (int u = 0; u < 4; ++u) av[u] = As[k][ty * 4 + u];
            #pragma unroll
            for (int u = 0; u < 4; ++u) bv[u] = Bs[k][tx * 4 + u];
            #pragma unroll
            for (int i2 = 0; i2 < 4; ++i2)
                #pragma unroll
                for (int j = 0; j < 4; ++j)
                    acc[i2][j] = fmaf(av[i2], bv[j], acc[i2][j]);
        }
        __syncthreads();
    }
    #pragma unroll
    for (int i2 = 0; i2 < 4; ++i2) {
        int gr = bm + ty * 4 + i2;
        if (gr < M) {
            float4 o = make_float4(acc[i2][0], acc[i2][1], acc[i2][2], acc[i2][3]);
            *(float4*)(C + (size_t)gr * N + bn + tx * 4) = o;
        }
    }
}

// ---------------- edge scatter, 256 features (one wave64 per edge, float4/lane) ----------------
__global__ __launch_bounds__(256) void scatter_add_256(const int* __restrict__ row,
                                                       const int* __restrict__ col,
                                                       const float* __restrict__ dinv,
                                                       const float* __restrict__ H,
                                                       float* __restrict__ AGG, int E) {
    int w = (blockIdx.x * 256 + threadIdx.x) >> 6;
    int lane = threadIdx.x & 63;
    if (w >= E) return;
    int r = row[w], c = col[w];
    float nrm = dinv[r] * dinv[c];
    float4 v = ((const float4*)(H + (size_t)c * 256))[lane];
    float* dst = AGG + (size_t)r * 256 + lane * 4;
    atomicAdd(dst + 0, v.x * nrm);
    atomicAdd(dst + 1, v.y * nrm);
    atomicAdd(dst + 2, v.z * nrm);
    atomicAdd(dst + 3, v.w * nrm);
}

// ---------------- edge scatter, 64 features (one wave64 per edge, 1 float/lane) ----------------
__global__ __launch_bounds__(256) void scatter_add_64(const int* __restrict__ row,
                                                      const int* __restrict__ col,
                                                      const float* __restrict__ dinv,
                                                      const float* __restrict__ H,
                                                      float* __restrict__ AGG, int E) {
    int w = (blockIdx.x * 256 + threadIdx.x) >> 6;
    int lane = threadIdx.x & 63;
    if (w >= E) return;
    int r = row[w], c = col[w];
    float nrm = dinv[r] * dinv[c];
    float v = H[(size_t)c * 64 + lane];
    atomicAdd(&AGG[(size_t)r * 64 + lane], v * nrm);
}

// ---------------- layer-1 finalize: self-loop + bias + relu (in place on AGG1) ----------------
__global__ __launch_bounds__(256) void finalize_relu(float* __restrict__ AGG,
                                                     const float* __restrict__ H,
                                                     const float* __restrict__ dinv,
                                                     const float* __restrict__ b, int n) {
    size_t idx = (size_t)blockIdx.x * 256 + threadIdx.x;   // grid = n blocks -> n*256 elems
    int node = (int)(idx >> 8), f = (int)(idx & 255);
    float di = dinv[node];
    float v = AGG[idx] + H[idx] * di * di + b[f];
    AGG[idx] = v > 0.f ? v : 0.f;
}

// ---------------- layer-2 finalize: self-loop + bias (in place on AGG2) ----------------
__global__ __launch_bounds__(256) void selfadd2(float* __restrict__ AGG,
                                                const float* __restrict__ H,
                                                const float* __restrict__ dinv,
                                                const float* __restrict__ b, int n) {
    int idx = blockIdx.x * 256 + threadIdx.x;              // n*64 total
    if (idx >= n * 64) return;
    int node = idx >> 6, f = idx & 63;
    float di = dinv[node];
    AGG[idx] += H[idx] * di * di + b[f];
}

// ---------------- log_softmax (wave64 == 64 features) + broadcast 24 copies ----------------
__global__ __launch_bounds__(256) void final_out(const float* __restrict__ AGG2,
                                                 float* __restrict__ out, int n, int copies) {
    int w = (blockIdx.x * 256 + threadIdx.x) >> 6;
    int lane = threadIdx.x & 63;
    if (w >= n) return;
    size_t base = (size_t)w * 64 + lane;
    float v = AGG2[base];
    float m = v;
    #pragma unroll
    for (int off = 32; off > 0; off >>= 1) m = fmaxf(m, __shfl_xor(m, off, 64));
    float e = expf(v - m);
    float s = e;
    #pragma unroll
    for (int off = 32; off > 0; off >>= 1) s += __shfl_xor(s, off, 64);
    float res = v - m - logf(s);
    size_t stride = (size_t)n * 64;
    for (int c = 0; c < copies; ++c) out[(size_t)c * stride + base] = res;
}

extern "C" void kernel_launch(void* const* d_in, const int* in_sizes, int n_in,
                              void* d_out, int out_size, void* d_ws, size_t ws_size,
                              hipStream_t stream) {
    const float* x  = (const float*)d_in[0];
    const float* W1 = (const float*)d_in[1];
    const float* b1 = (const float*)d_in[2];
    const float* W2 = (const float*)d_in[3];
    const float* b2 = (const float*)d_in[4];
    const int*   ei = (const int*)d_in[5];

    const int n = in_sizes[0] / 128;          // 50000
    const int E = in_sizes[5] / 2;            // 800000
    float* out = (float*)d_out;
    const size_t stride = (size_t)n * 64;     // one broadcast-copy region
    const int copies = (int)(out_size / stride);  // 24

    // d_out doubles as workspace (all scratch regions are dead or same-wave-read
    // by the time final_out overwrites them):
    float* deg  = out;                        // region 0      (n floats)
    float* H1   = out + 16 * stride;          // regions 16-19 (n*256) ; later H2 = first n*64
    float* AGG1 = out + 20 * stride;          // regions 20-23 (n*256) ; later AGG2 = first n*64
    float* H2   = H1;
    float* AGG2 = AGG1;

    // zero AGG1 before edge scatter
    hipMemsetAsync(AGG1, 0, (size_t)n * 256 * sizeof(float), stream);

    // degree -> dinv (stored in deg)
    init_deg <<<(n + 255) / 256, 256, 0, stream>>>(deg, n);
    deg_edges<<<(E + 255) / 256, 256, 0, stream>>>(ei, deg, E);
    make_dinv<<<(n + 255) / 256, 256, 0, stream>>>(deg, n);

    // layer 1: H1 = x @ W1 ; scatter ; self-loop+bias+relu
    gemm64<<<dim3((n + 63) / 64, 4), 256, 0, stream>>>(x, W1, H1, n, 256, 128);
    scatter_add_256<<<(E + 3) / 4, 256, 0, stream>>>(ei, ei + E, deg, H1, AGG1, E);
    finalize_relu<<<n, 256, 0, stream>>>(AGG1, H1, deg, b1, n);

    // layer 2: H2 = AGG1 @ W2 ; scatter ; self-loop+bias
    gemm64<<<dim3((n + 63) / 64, 1), 256, 0, stream>>>(AGG1, W2, H2, n, 64, 256);
    hipMemsetAsync(AGG2, 0, (size_t)n * 64 * sizeof(float), stream);
    scatter_add_64<<<(E + 3) / 4, 256, 0, stream>>>(ei, ei + E, deg, H2, AGG2, E);
    selfadd2<<<(n * 64 + 255) / 256, 256, 0, stream>>>(AGG2, H2, deg, b2, n);

    // log_softmax + broadcast all 24 copies (overwrites every byte of d_out)
    final_out<<<(n + 3) / 4, 256, 0, stream>>>(AGG2, out, n, copies);
}

// Round 2
// 710.587 us; speedup vs baseline: 4.7983x; 4.7983x over previous
//
#include <hip/hip_runtime.h>

// ============ CSR bucket build (no scan needed — bucket order is irrelevant) ============
__global__ __launch_bounds__(256) void hist_rows(const int* __restrict__ row, int* __restrict__ cnt, int E) {
    int e = blockIdx.x * 256 + threadIdx.x;
    if (e < E) atomicAdd(&cnt[row[e]], 1);
}

__global__ __launch_bounds__(256) void alloc_buckets(const int* __restrict__ cnt,
                                                     int* __restrict__ base, int* __restrict__ fill,
                                                     float* __restrict__ dinv,
                                                     int* __restrict__ total, int n) {
    int i = blockIdx.x * 256 + threadIdx.x;
    if (i >= n) return;
    int c = cnt[i];
    int b = atomicAdd(total, c);
    base[i] = b;
    fill[i] = b;
    dinv[i] = rsqrtf(1.0f + (float)c);   // +1 self-loop
}

__global__ __launch_bounds__(256) void fill_buckets(const int* __restrict__ row, const int* __restrict__ col,
                                                    int* __restrict__ fill, int* __restrict__ cols, int E) {
    int e = blockIdx.x * 256 + threadIdx.x;
    if (e < E) {
        int pos = atomicAdd(&fill[row[e]], 1);
        cols[pos] = col[e];
    }
}

// ============ aggregate x (128 feats): AGGX[i] = dinv_i^2 * x[i] + sum_e dinv_i*dinv_c * x[c] ============
__global__ __launch_bounds__(256) void agg_x(const float* __restrict__ x,
                                             const int* __restrict__ base, const int* __restrict__ cnt,
                                             const int* __restrict__ cols, const float* __restrict__ dinv,
                                             float* __restrict__ AGGX, int n) {
    int w = (blockIdx.x * 256 + threadIdx.x) >> 6;
    int lane = threadIdx.x & 63;
    if (w >= n) return;
    float di = dinv[w];
    float2 xv = ((const float2*)(x + (size_t)w * 128))[lane];
    float2 acc = make_float2(xv.x * di * di, xv.y * di * di);
    int b0 = base[w], deg = cnt[w];
    for (int s = 0; s < deg; s += 64) {
        int seg = min(64, deg - s);
        int myc = 0; float myd = 0.f;
        if (lane < seg) { myc = cols[b0 + s + lane]; myd = dinv[myc]; }
        for (int j = 0; j < seg; ++j) {
            int c = __shfl(myc, j, 64);
            float nrm = di * __shfl(myd, j, 64);
            float2 v = ((const float2*)(x + (size_t)c * 128))[lane];
            acc.x = fmaf(v.x, nrm, acc.x);
            acc.y = fmaf(v.y, nrm, acc.y);
        }
    }
    ((float2*)(AGGX + (size_t)w * 128))[lane] = acc;
}

// ============ aggregate H2 (64 feats) + bias: AGG2[i] = ... + b2 ============
__global__ __launch_bounds__(256) void agg_h2(const float* __restrict__ H2,
                                              const int* __restrict__ base, const int* __restrict__ cnt,
                                              const int* __restrict__ cols, const float* __restrict__ dinv,
                                              const float* __restrict__ b2,
                                              float* __restrict__ AGG2, int n) {
    int w = (blockIdx.x * 256 + threadIdx.x) >> 6;
    int lane = threadIdx.x & 63;
    if (w >= n) return;
    float di = dinv[w];
    float acc = H2[(size_t)w * 64 + lane] * di * di;
    int b0 = base[w], deg = cnt[w];
    for (int s = 0; s < deg; s += 64) {
        int seg = min(64, deg - s);
        int myc = 0; float myd = 0.f;
        if (lane < seg) { myc = cols[b0 + s + lane]; myd = dinv[myc]; }
        for (int j = 0; j < seg; ++j) {
            int c = __shfl(myc, j, 64);
            float nrm = di * __shfl(myd, j, 64);
            acc = fmaf(H2[(size_t)c * 64 + lane], nrm, acc);
        }
    }
    AGG2[(size_t)w * 64 + lane] = acc + b2[lane];
}

// ============ fp32 tiled GEMM: C = A[M,K]@B[K,N] (+bias, relu optional) ============
__global__ __launch_bounds__(256) void gemm64(const float* __restrict__ A,
                                              const float* __restrict__ B,
                                              const float* __restrict__ bias,
                                              float* __restrict__ C,
                                              int M, int N, int K, int relu) {
    __shared__ float As[32][65];
    __shared__ float Bs[32][65];
    const int bm = blockIdx.x * 64;
    const int bn = blockIdx.y * 64;
    const int tid = threadIdx.x;
    const int tx = tid & 15;
    const int ty = tid >> 4;
    float acc[4][4] = {};

    for (int k0 = 0; k0 < K; k0 += 32) {
        #pragma unroll
        for (int i = 0; i < 8; ++i) {
            int t = tid + i * 256;
            int r = t >> 5, c = t & 31;
            int gr = bm + r;
            float v = 0.f;
            if (gr < M) v = A[(size_t)gr * K + k0 + c];
            As[c][r] = v;
        }
        #pragma unroll
        for (int i = 0; i < 8; ++i) {
            int t = tid + i * 256;
            int r = t >> 6, c = t & 63;
            Bs[r][c] = B[(size_t)(k0 + r) * N + bn + c];
        }
        __syncthreads();
        #pragma unroll
        for (int k = 0; k < 32; ++k) {
            float av[4], bv[4];
            #pragma unroll
            for (int u = 0; u < 4; ++u) av[u] = As[k][ty * 4 + u];
            #pragma unroll
            for (int u = 0; u < 4; ++u) bv[u] = Bs[k][tx * 4 + u];
            #pragma unroll
            for (int i2 = 0; i2 < 4; ++i2)
                #pragma unroll
                for (int j = 0; j < 4; ++j)
                    acc[i2][j] = fmaf(av[i2], bv[j], acc[i2][j]);
        }
        __syncthreads();
    }
    float bv4[4];
    #pragma unroll
    for (int j = 0; j < 4; ++j) bv4[j] = bias ? bias[bn + tx * 4 + j] : 0.f;
    #pragma unroll
    for (int i2 = 0; i2 < 4; ++i2) {
        int gr = bm + ty * 4 + i2;
        if (gr < M) {
            float4 o;
            o.x = acc[i2][0] + bv4[0];
            o.y = acc[i2][1] + bv4[1];
            o.z = acc[i2][2] + bv4[2];
            o.w = acc[i2][3] + bv4[3];
            if (relu) {
                o.x = fmaxf(o.x, 0.f); o.y = fmaxf(o.y, 0.f);
                o.z = fmaxf(o.z, 0.f); o.w = fmaxf(o.w, 0.f);
            }
            *(float4*)(C + (size_t)gr * N + bn + tx * 4) = o;
        }
    }
}

// ============ log_softmax (wave64 = 64 feats) + broadcast 24 copies ============
__global__ __launch_bounds__(256) void final_out(const float* __restrict__ AGG2,
                                                 float* __restrict__ out, int n, int copies) {
    int w = (blockIdx.x * 256 + threadIdx.x) >> 6;
    int lane = threadIdx.x & 63;
    if (w >= n) return;
    size_t idx = (size_t)w * 64 + lane;
    float v = AGG2[idx];
    float m = v;
    #pragma unroll
    for (int off = 32; off > 0; off >>= 1) m = fmaxf(m, __shfl_xor(m, off, 64));
    float e = expf(v - m);
    float s = e;
    #pragma unroll
    for (int off = 32; off > 0; off >>= 1) s += __shfl_xor(s, off, 64);
    float res = v - m - logf(s);
    size_t stride = (size_t)n * 64;
    for (int c = 0; c < copies; ++c) out[(size_t)c * stride + idx] = res;
}

extern "C" void kernel_launch(void* const* d_in, const int* in_sizes, int n_in,
                              void* d_out, int out_size, void* d_ws, size_t ws_size,
                              hipStream_t stream) {
    const float* x  = (const float*)d_in[0];
    const float* W1 = (const float*)d_in[1];
    const float* b1 = (const float*)d_in[2];
    const float* W2 = (const float*)d_in[3];
    const float* b2 = (const float*)d_in[4];
    const int*   ei = (const int*)d_in[5];

    const int n = in_sizes[0] / 128;              // 50000
    const int E = in_sizes[5] / 2;                // 800000
    float* out = (float*)d_out;
    const size_t stride = (size_t)n * 64;         // one broadcast-copy region (12.8 MB)
    const int copies = (int)(out_size / stride);  // 24

    // ---- d_out doubles as workspace (regions dead before final_out rewrites them) ----
    // region 0: dinv(n) | cnt(n int) | base(n int) | fill(n int) | total(1 int)
    float* dinv  = out;
    int*   cnt   = (int*)(out + n);
    int*   base  = (int*)(out + 2 * (size_t)n);
    int*   fill  = (int*)(out + 3 * (size_t)n);
    int*   total = (int*)(out + 4 * (size_t)n);
    int*   cols  = (int*)(out + 1 * stride);      // region 1: E ints (3.2 MB)
    float* AGGX  = out + 2 * stride;              // regions 2-3: n*128
    float* H1    = out + 4 * stride;              // regions 4-7: n*256
    float* H2    = out + 8 * stride;              // region 8:    n*64
    float* AGG2  = out + 9 * stride;              // region 9:    n*64

    // zero cnt..total in one shot
    hipMemsetAsync(cnt, 0, (3 * (size_t)n + 64) * sizeof(int), stream);

    // bucket build
    hist_rows   <<<(E + 255) / 256, 256, 0, stream>>>(ei, cnt, E);
    alloc_buckets<<<(n + 255) / 256, 256, 0, stream>>>(cnt, base, fill, dinv, total, n);
    fill_buckets<<<(E + 255) / 256, 256, 0, stream>>>(ei, ei + E, fill, cols, E);

    // layer 1: aggregate-then-transform (A(xW) == (Ax)W)
    agg_x<<<(n + 3) / 4, 256, 0, stream>>>(x, base, cnt, cols, dinv, AGGX, n);
    gemm64<<<dim3((n + 63) / 64, 4), 256, 0, stream>>>(AGGX, W1, b1, H1, n, 256, 128, 1);

    // layer 2: transform-then-aggregate (64 < 256 feats)
    gemm64<<<dim3((n + 63) / 64, 1), 256, 0, stream>>>(H1, W2, nullptr, H2, n, 64, 256, 0);
    agg_h2<<<(n + 3) / 4, 256, 0, stream>>>(H2, base, cnt, cols, dinv, b2, AGG2, n);

    // log_softmax + broadcast (overwrites every byte of d_out)
    final_out<<<(n + 3) / 4, 256, 0, stream>>>(AGG2, out, n, copies);
}

// Round 3
// 610.933 us; speedup vs baseline: 5.5809x; 1.1631x over previous
//
#include <hip/hip_runtime.h>

// ============ CSR bucket build (order-free; buckets padded to multiple of 8) ============
__global__ __launch_bounds__(256) void hist_rows(const int* __restrict__ row, int* __restrict__ cnt, int E) {
    int e = blockIdx.x * 256 + threadIdx.x;
    if (e < E) atomicAdd(&cnt[row[e]], 1);
}

__global__ __launch_bounds__(256) void alloc_buckets(const int* __restrict__ cnt,
                                                     int* __restrict__ base, int* __restrict__ fill,
                                                     float* __restrict__ dinv,
                                                     int* __restrict__ total, int n) {
    int i = blockIdx.x * 256 + threadIdx.x;
    if (i >= n) return;
    int c = cnt[i];
    int cp = (c + 7) & ~7;                 // pad to x8 (pad slots stay {0, norm=0} -> contribute 0)
    int b = atomicAdd(total, cp);
    base[i] = b;
    fill[i] = b;
    dinv[i] = rsqrtf(1.0f + (float)c);     // +1 self-loop
}

// pack {col, norm=dinv[r]*dinv[c]} per edge; bucket slot claimed via atomic
__global__ __launch_bounds__(256) void fill_buckets(const int* __restrict__ row, const int* __restrict__ col,
                                                    int* __restrict__ fill, const float* __restrict__ dinv,
                                                    int2* __restrict__ edge2, int E) {
    int e = blockIdx.x * 256 + threadIdx.x;
    if (e < E) {
        int r = row[e], c = col[e];
        int pos = atomicAdd(&fill[r], 1);
        edge2[pos] = make_int2(c, __float_as_int(dinv[r] * dinv[c]));
    }
}

// ============ aggregate x (128 feats, float2/lane): AGGX[i] = dinv_i^2*x[i] + sum nrm_e*x[col_e] ============
__global__ __launch_bounds__(256) void agg_x(const float* __restrict__ x,
                                             const int* __restrict__ base, const int* __restrict__ cnt,
                                             const int2* __restrict__ edge2, const float* __restrict__ dinv,
                                             float* __restrict__ AGGX, int n) {
    int w = (blockIdx.x * 256 + threadIdx.x) >> 6;
    int lane = threadIdx.x & 63;
    if (w >= n) return;
    float di = dinv[w];
    float2 xv = ((const float2*)(x + (size_t)w * 128))[lane];
    float2 a0 = make_float2(xv.x * di * di, xv.y * di * di);
    float2 a1 = make_float2(0.f, 0.f), a2 = a1, a3 = a1;
    const int2* eb = edge2 + base[w];
    int dp = (cnt[w] + 7) & ~7;
    for (int j = 0; j < dp; j += 8) {
        int2 e[8];
        #pragma unroll
        for (int u = 0; u < 8; ++u) e[u] = eb[j + u];          // wave-uniform broadcast loads
        float2 v[8];
        #pragma unroll
        for (int u = 0; u < 8; ++u)                            // 8 gathers in flight
            v[u] = ((const float2*)(x + (size_t)e[u].x * 128))[lane];
        #pragma unroll
        for (int u = 0; u < 8; ++u) {
            float nr = __int_as_float(e[u].y);
            float2* a = (u & 3) == 0 ? &a0 : (u & 3) == 1 ? &a1 : (u & 3) == 2 ? &a2 : &a3;
            a->x = fmaf(v[u].x, nr, a->x);
            a->y = fmaf(v[u].y, nr, a->y);
        }
    }
    float2 o = make_float2(a0.x + a1.x + a2.x + a3.x, a0.y + a1.y + a2.y + a3.y);
    ((float2*)(AGGX + (size_t)w * 128))[lane] = o;
}

// ============ aggregate H2 (64 feats, 1 float/lane) + bias ============
__global__ __launch_bounds__(256) void agg_h2(const float* __restrict__ H2,
                                              const int* __restrict__ base, const int* __restrict__ cnt,
                                              const int2* __restrict__ edge2, const float* __restrict__ dinv,
                                              const float* __restrict__ b2,
                                              float* __restrict__ AGG2, int n) {
    int w = (blockIdx.x * 256 + threadIdx.x) >> 6;
    int lane = threadIdx.x & 63;
    if (w >= n) return;
    float di = dinv[w];
    float a0 = H2[(size_t)w * 64 + lane] * di * di;
    float a1 = 0.f, a2 = 0.f, a3 = 0.f;
    const int2* eb = edge2 + base[w];
    int dp = (cnt[w] + 7) & ~7;
    for (int j = 0; j < dp; j += 8) {
        int2 e[8];
        #pragma unroll
        for (int u = 0; u < 8; ++u) e[u] = eb[j + u];
        float v[8];
        #pragma unroll
        for (int u = 0; u < 8; ++u)
            v[u] = H2[(size_t)e[u].x * 64 + lane];
        #pragma unroll
        for (int u = 0; u < 8; ++u) {
            float nr = __int_as_float(e[u].y);
            float* a = (u & 3) == 0 ? &a0 : (u & 3) == 1 ? &a1 : (u & 3) == 2 ? &a2 : &a3;
            *a = fmaf(v[u], nr, *a);
        }
    }
    AGG2[(size_t)w * 64 + lane] = a0 + a1 + a2 + a3 + b2[lane];
}

// ============ fp32 tiled GEMM: C = A[M,K]@B[K,N] (+bias, relu optional) ============
__global__ __launch_bounds__(256) void gemm64(const float* __restrict__ A,
                                              const float* __restrict__ B,
                                              const float* __restrict__ bias,
                                              float* __restrict__ C,
                                              int M, int N, int K, int relu) {
    __shared__ float As[32][68];   // pad 68: keeps &As[k][4t] 16B-aligned -> ds_read_b128
    __shared__ float Bs[32][68];
    const int bm = blockIdx.x * 64;
    const int bn = blockIdx.y * 64;
    const int tid = threadIdx.x;
    const int tx = tid & 15;
    const int ty = tid >> 4;
    float acc[4][4] = {};

    for (int k0 = 0; k0 < K; k0 += 32) {
        #pragma unroll
        for (int i = 0; i < 8; ++i) {        // A tile 64x32
            int t = tid + i * 256;
            int r = t >> 5, c = t & 31;
            int gr = bm + r;
            float v = 0.f;
            if (gr < M) v = A[(size_t)gr * K + k0 + c];
            As[c][r] = v;
        }
        #pragma unroll
        for (int i = 0; i < 8; ++i) {        // B tile 32x64
            int t = tid + i * 256;
            int r = t >> 6, c = t & 63;
            Bs[r][c] = B[(size_t)(k0 + r) * N + bn + c];
        }
        __syncthreads();
        #pragma unroll
        for (int k = 0; k < 32; ++k) {
            float4 av = *(const float4*)&As[k][ty * 4];
            float4 bv = *(const float4*)&Bs[k][tx * 4];
            float a4[4] = {av.x, av.y, av.z, av.w};
            float b4[4] = {bv.x, bv.y, bv.z, bv.w};
            #pragma unroll
            for (int i2 = 0; i2 < 4; ++i2)
                #pragma unroll
                for (int j = 0; j < 4; ++j)
                    acc[i2][j] = fmaf(a4[i2], b4[j], acc[i2][j]);
        }
        __syncthreads();
    }
    float bv4[4];
    #pragma unroll
    for (int j = 0; j < 4; ++j) bv4[j] = bias ? bias[bn + tx * 4 + j] : 0.f;
    #pragma unroll
    for (int i2 = 0; i2 < 4; ++i2) {
        int gr = bm + ty * 4 + i2;
        if (gr < M) {
            float4 o;
            o.x = acc[i2][0] + bv4[0];
            o.y = acc[i2][1] + bv4[1];
            o.z = acc[i2][2] + bv4[2];
            o.w = acc[i2][3] + bv4[3];
            if (relu) {
                o.x = fmaxf(o.x, 0.f); o.y = fmaxf(o.y, 0.f);
                o.z = fmaxf(o.z, 0.f); o.w = fmaxf(o.w, 0.f);
            }
            *(float4*)(C + (size_t)gr * N + bn + tx * 4) = o;
        }
    }
}

// ============ log_softmax (wave64 = 64 feats) + broadcast 24 copies ============
__global__ __launch_bounds__(256) void final_out(const float* __restrict__ AGG2,
                                                 float* __restrict__ out, int n, int copies) {
    int w = (blockIdx.x * 256 + threadIdx.x) >> 6;
    int lane = threadIdx.x & 63;
    if (w >= n) return;
    size_t idx = (size_t)w * 64 + lane;
    float v = AGG2[idx];
    float m = v;
    #pragma unroll
    for (int off = 32; off > 0; off >>= 1) m = fmaxf(m, __shfl_xor(m, off, 64));
    float e = expf(v - m);
    float s = e;
    #pragma unroll
    for (int off = 32; off > 0; off >>= 1) s += __shfl_xor(s, off, 64);
    float res = v - m - logf(s);
    size_t stride = (size_t)n * 64;
    for (int c = 0; c < copies; ++c) out[(size_t)c * stride + idx] = res;
}

extern "C" void kernel_launch(void* const* d_in, const int* in_sizes, int n_in,
                              void* d_out, int out_size, void* d_ws, size_t ws_size,
                              hipStream_t stream) {
    const float* x  = (const float*)d_in[0];
    const float* W1 = (const float*)d_in[1];
    const float* b1 = (const float*)d_in[2];
    const float* W2 = (const float*)d_in[3];
    const float* b2 = (const float*)d_in[4];
    const int*   ei = (const int*)d_in[5];

    const int n = in_sizes[0] / 128;              // 50000
    const int E = in_sizes[5] / 2;                // 800000
    float* out = (float*)d_out;
    const size_t stride = (size_t)n * 64;         // one broadcast-copy region (3.2M floats)
    const int copies = (int)(out_size / stride);  // 24

    // ---- d_out doubles as workspace (regions dead or same-wave-read before final_out) ----
    float* dinv  = out;                           // region 0
    int*   cnt   = (int*)(out + n);
    int*   base  = (int*)(out + 2 * (size_t)n);
    int*   fill  = (int*)(out + 3 * (size_t)n);
    int*   total = (int*)(out + 4 * (size_t)n);
    int2*  edge2 = (int2*)(out + 1 * stride);     // region 1: (E + 8n) int2 = 9.6 MB < 12.8 MB
    float* AGGX  = out + 2 * stride;              // regions 2-3
    float* H1    = out + 4 * stride;              // regions 4-7
    float* H2    = out + 8 * stride;              // region 8
    float* AGG2  = out + 9 * stride;              // region 9

    // zero cnt/base/fill/total + edge2 (pad slots must be {0,0})
    hipMemsetAsync(cnt, 0, (3 * (size_t)n + 64) * sizeof(int), stream);
    hipMemsetAsync(edge2, 0, ((size_t)E + 8 * (size_t)n) * sizeof(int2), stream);

    // bucket build
    hist_rows    <<<(E + 255) / 256, 256, 0, stream>>>(ei, cnt, E);
    alloc_buckets<<<(n + 255) / 256, 256, 0, stream>>>(cnt, base, fill, dinv, total, n);
    fill_buckets <<<(E + 255) / 256, 256, 0, stream>>>(ei, ei + E, fill, dinv, edge2, E);

    // layer 1: aggregate-then-transform (A(xW) == (Ax)W)
    agg_x<<<(n + 3) / 4, 256, 0, stream>>>(x, base, cnt, edge2, dinv, AGGX, n);
    gemm64<<<dim3((n + 63) / 64, 4), 256, 0, stream>>>(AGGX, W1, b1, H1, n, 256, 128, 1);

    // layer 2: transform-then-aggregate (64 < 256 feats)
    gemm64<<<dim3((n + 63) / 64, 1), 256, 0, stream>>>(H1, W2, nullptr, H2, n, 64, 256, 0);
    agg_h2<<<(n + 3) / 4, 256, 0, stream>>>(H2, base, cnt, edge2, dinv, b2, AGG2, n);

    // log_softmax + broadcast (overwrites every byte of d_out)
    final_out<<<(n + 3) / 4, 256, 0, stream>>>(AGG2, out, n, copies);
}